// Round 4
// baseline (296.696 us; speedup 1.0000x reference)
//
#include <hip/hip_runtime.h>
#include <hip/hip_bf16.h>

#define DEV_INLINE __device__ __forceinline__

typedef float v2f __attribute__((ext_vector_type(2)));
typedef __fp16 h2v __attribute__((ext_vector_type(2)));   // matches cvt_pkrtz return type

DEV_INLINE int rl_i(int v, int l) { return __builtin_amdgcn_readlane(v, l); }
DEV_INLINE float sigmoid_f(float x) { return __builtin_amdgcn_rcpf(1.0f + __expf(-x)); }

#if __has_builtin(__builtin_amdgcn_fdot2)
DEV_INLINE float fdot2(h2v a, h2v b, float c) { return __builtin_amdgcn_fdot2(a, b, c, false); }
#else
DEV_INLINE float fdot2(h2v a, h2v b, float c) {
    return fmaf((float)a[0], (float)b[0], fmaf((float)a[1], (float)b[1], c));
}
#endif

// ---------------- pass 1: embW[v] = emb[v,:] @ W1 + b1 ----------------
// Row layout pair-interleaved: float2 {z[j], z[j+64]} at pair index j (j=0..63),
// so the recurrent kernel's lane `l` loads its two gate columns {l, l+64} with
// one coalesced global_load_dwordx2.
__global__ __launch_bounds__(128) void embw_kernel(
    const float* __restrict__ emb, const float* __restrict__ W1,
    const float* __restrict__ b1, float* __restrict__ embW)
{
    const int v = blockIdx.x, c = threadIdx.x;   // c = gate column 0..127
    __shared__ float e[32];
    if (c < 32) e[c] = emb[v * 32 + c];
    __syncthreads();
    float acc = b1[c];
#pragma unroll
    for (int d = 0; d < 32; ++d) acc = fmaf(e[d], W1[d * 128 + c], acc);
    embW[v * 128 + ((c & 63) << 1) + (c >> 6)] = acc;
}

// ---------------- pass 2: recurrent kernel ----------------
// One wave = one batch element. Lane l owns gate columns ca=l (i|f) and
// cb=l+64 (g|o). Input contribution gathered from embW (f32, exact);
// h@U1 via v_dot2_f32_f16 (f16 weights in 32 VGPRs, f32 accumulate).
// MODE 0: embW table in d_ws.  MODE 1: fallback, compute e@W1 in-loop.
template<int MODE>
__global__ __launch_bounds__(256) void lstm_kernel(
    const int* __restrict__ x, const float* __restrict__ embW,
    const float* __restrict__ emb, const float* __restrict__ W1,
    const float* __restrict__ b1, const float* __restrict__ U1,
    const float* __restrict__ W2, const float* __restrict__ U2,
    const float* __restrict__ b2, float* __restrict__ out, int T)
{
    const int lane = threadIdx.x & 63;
    const int wave = threadIdx.x >> 6;
    const int b    = blockIdx.x * 4 + wave;
    const bool low = lane < 32;
    const int ca = lane, cb = lane + 64;

    // U1 columns as packed-f16 k-pairs: 32 VGPRs total (RTNE via __fp16 cast)
    h2v upa[16], upb[16];
#pragma unroll
    for (int m = 0; m < 16; ++m) {
        h2v ta, tb;
        ta[0] = (__fp16)U1[(2 * m) * 128 + ca];
        ta[1] = (__fp16)U1[(2 * m + 1) * 128 + ca];
        tb[0] = (__fp16)U1[(2 * m) * 128 + cb];
        tb[1] = (__fp16)U1[(2 * m + 1) * 128 + cb];
        upa[m] = ta; upb[m] = tb;
    }

    h2v wpa[16], wpb[16];            // MODE1 only (DCE'd in MODE0)
    float ba = 0.f, bb = 0.f;
    if constexpr (MODE == 1) {
#pragma unroll
        for (int m = 0; m < 16; ++m) {
            h2v ta, tb;
            ta[0] = (__fp16)W1[(2 * m) * 128 + ca];
            ta[1] = (__fp16)W1[(2 * m + 1) * 128 + ca];
            tb[0] = (__fp16)W1[(2 * m) * 128 + cb];
            tb[1] = (__fp16)W1[(2 * m + 1) * 128 + cb];
            wpa[m] = ta; wpb[m] = tb;
        }
        ba = b1[ca]; bb = b1[cb];
    }

    // layer 2 (H=1): 16-lane group g = lane>>4 owns gate g; order i,f,g,o
    const int gsel = lane >> 4;
    const int e0 = lane & 15, e1 = (lane & 15) + 16;
    const float w2a = W2[e0 * 4 + gsel];
    const float w2b = W2[e1 * 4 + gsel];
    const float u2s = U2[gsel];
    const float b2s = b2[gsel];

    const int* xrow = x + b * T;

    float h = 0.f, c = 0.f, h2 = 0.f, c2 = 0.f;

    int idxA = __builtin_amdgcn_readfirstlane(xrow[0]);   // idx for t=0
    int idxB = __builtin_amdgcn_readfirstlane(xrow[1]);   // idx for t=1

    v2f zc;           // input-part pair {z[ca], z[cb]} for current t (MODE0)
    float ec[32];     // e row for current t (MODE1)
    if constexpr (MODE == 0) {
        zc = reinterpret_cast<const v2f*>(embW)[idxA * 64 + lane];
    } else {
#pragma unroll
        for (int d = 0; d < 32; ++d) ec[d] = emb[idxA * 32 + d];
    }

#pragma unroll 2
    for (int t = 0; t < T; ++t) {
        // ---- prefetch input contribution for t+1 (hides under this step) ----
        v2f zn;
        float en[32];
        if constexpr (MODE == 0) {
            zn = reinterpret_cast<const v2f*>(embW)[idxB * 64 + lane];
        } else {
#pragma unroll
            for (int d = 0; d < 32; ++d) en[d] = emb[idxB * 32 + d];
        }
        idxB = __builtin_amdgcn_readfirstlane(xrow[(t + 2 < T) ? (t + 2) : (T - 1)]);

        // ---- z = z_input + h @ U1 ----
        float za0, zb0;
        if constexpr (MODE == 0) {
            za0 = zc.x; zb0 = zc.y;               // bias already folded in
        } else {
            za0 = ba; zb0 = bb;
#pragma unroll
            for (int m = 0; m < 16; ++m) {
                h2v ep = __builtin_amdgcn_cvt_pkrtz(ec[2 * m], ec[2 * m + 1]);
                za0 = fdot2(ep, wpa[m], za0);
                zb0 = fdot2(ep, wpb[m], zb0);
            }
        }
        // pack h pairs: even lane 2m holds {h[2m], h[2m+1]}
        float hx = __shfl_xor(h, 1);
        int hpi = __builtin_bit_cast(int, __builtin_amdgcn_cvt_pkrtz(h, hx));
        float za1 = 0.f, zb1 = 0.f;
#pragma unroll
        for (int m = 0; m < 16; m += 2) {
            h2v h0 = __builtin_bit_cast(h2v, rl_i(hpi, 2 * m));
            h2v h1 = __builtin_bit_cast(h2v, rl_i(hpi, 2 * m + 2));
            za0 = fdot2(h0, upa[m],     za0);
            zb0 = fdot2(h0, upb[m],     zb0);
            za1 = fdot2(h1, upa[m + 1], za1);
            zb1 = fdot2(h1, upb[m + 1], zb1);
        }
        const float za = za0 + za1;   // z_i (low) | z_f (high)
        const float zb = zb0 + zb1;   // z_g (low) | z_o (high)

        // ---- layer-1 gates ----
        float sa = sigmoid_f(za);                    // sig(i) | sig(f)
        float xb_ = low ? 2.0f * zb : zb;
        float u  = sigmoid_f(xb_);
        float rb = low ? 2.0f * u - 1.0f : u;        // tanh(g) | sig(o)

        float sa_x = __shfl_xor(sa, 32);
        float rb_x = __shfl_xor(rb, 32);
        float iv = low ? sa   : sa_x;
        float fv = low ? sa_x : sa;
        float gv = low ? rb   : rb_x;
        float ov = low ? rb_x : rb;

        c = fmaf(fv, c, iv * gv);
        float tc = 2.0f * sigmoid_f(2.0f * c) - 1.0f;   // tanh(c)
        h = ov * tc;   // lanes j and j+32 hold identical h[j&31]

        // ---- layer 2 (H=1): group-parallel dot + one wave-wide sigmoid ----
        float ha = __shfl(h, e0);
        float hb = __shfl(h, e1);
        float p = ha * w2a + hb * w2b;
        p += __shfl_xor(p, 1);
        p += __shfl_xor(p, 2);
        p += __shfl_xor(p, 4);
        p += __shfl_xor(p, 8);
        float s2 = sigmoid_f(p + fmaf(u2s, h2, b2s));   // all 4 gates at once
        float i2 = __uint_as_float(rl_i(__float_as_uint(s2), 0));
        float f2 = __uint_as_float(rl_i(__float_as_uint(s2), 16));
        float g2 = __uint_as_float(rl_i(__float_as_uint(s2), 32));
        float o2 = __uint_as_float(rl_i(__float_as_uint(s2), 48));
        c2 = fmaf(f2, c2, i2 * g2);
        h2 = o2 * sigmoid_f(c2);

        // rotate input buffers
        if constexpr (MODE == 0) {
            zc = zn;
        } else {
#pragma unroll
            for (int d = 0; d < 32; ++d) ec[d] = en[d];
        }
    }

    if (lane == 0) out[b] = h2;
}

extern "C" void kernel_launch(void* const* d_in, const int* in_sizes, int n_in,
                              void* d_out, int out_size, void* d_ws, size_t ws_size,
                              hipStream_t stream) {
    const int*   x   = (const int*)d_in[0];
    const float* emb = (const float*)d_in[1];
    const float* W1  = (const float*)d_in[2];
    const float* U1  = (const float*)d_in[3];
    const float* b1  = (const float*)d_in[4];
    const float* W2  = (const float*)d_in[5];
    const float* U2  = (const float*)d_in[6];
    const float* b2  = (const float*)d_in[7];
    float* out = (float*)d_out;

    const int V = in_sizes[1] / 32;       // vocab (30000)
    const int T = 200;
    const int B = in_sizes[0] / T;        // 4096
    const int blocks = B / 4;             // 4 waves (batch elems) per block

    const size_t need = (size_t)V * 128 * sizeof(float);   // 15.36 MB
    if (ws_size >= need) {
        float* embW = (float*)d_ws;
        embw_kernel<<<V, 128, 0, stream>>>(emb, W1, b1, embW);
        lstm_kernel<0><<<blocks, 256, 0, stream>>>(x, embW, emb, W1, b1, U1,
                                                   W2, U2, b2, out, T);
    } else {
        lstm_kernel<1><<<blocks, 256, 0, stream>>>(x, nullptr, emb, W1, b1, U1,
                                                   W2, U2, b2, out, T);
    }
}

// Round 5
// 293.285 us; speedup vs baseline: 1.0116x; 1.0116x over previous
//
#include <hip/hip_runtime.h>
#include <hip/hip_bf16.h>

#define DEV_INLINE __device__ __forceinline__

typedef float v2f __attribute__((ext_vector_type(2)));
typedef __fp16 h2v __attribute__((ext_vector_type(2)));   // matches cvt_pkrtz return type

DEV_INLINE int rl_i(int v, int l) { return __builtin_amdgcn_readlane(v, l); }
DEV_INLINE float rlf(float v, int l) {
    return __uint_as_float(__builtin_amdgcn_readlane(__float_as_uint(v), l));
}
DEV_INLINE float sigmoid_f(float x) { return __builtin_amdgcn_rcpf(1.0f + __expf(-x)); }

#if __has_builtin(__builtin_amdgcn_fdot2)
DEV_INLINE float fdot2(h2v a, h2v b, float c) { return __builtin_amdgcn_fdot2(a, b, c, false); }
#else
DEV_INLINE float fdot2(h2v a, h2v b, float c) {
    return fmaf((float)a[0], (float)b[0], fmaf((float)a[1], (float)b[1], c));
}
#endif

// lane^1 exchange via DPP quad_perm [1,0,3,2] (VALU, no DS)
DEV_INLINE float dpp_swap1(float v) {
    int r = __builtin_amdgcn_update_dpp(__float_as_int(v), __float_as_int(v),
                                        0xB1, 0xF, 0xF, false);
    return __int_as_float(r);
}

// Given per-lane v (low half holds A-values, high half holds B-values),
// produce lo_b = A[l&31] on ALL lanes, hi_b = B[l&31] on ALL lanes.
DEV_INLINE void bcast_halves(float v, bool low, float& lo_b, float& hi_b) {
#if __has_builtin(__builtin_amdgcn_permlane32_swap)
    auto r = __builtin_amdgcn_permlane32_swap(__float_as_uint(v), __float_as_uint(v),
                                              false, false);
    lo_b = __uint_as_float(r[0]);
    hi_b = __uint_as_float(r[1]);
#else
    float vx = __shfl_xor(v, 32);
    lo_b = low ? v : vx;
    hi_b = low ? vx : v;
#endif
}

// ---------------- pass 1: embW[v] = emb[v,:] @ W1 + b1 ----------------
// Pair-interleaved row: float2 {z[j], z[j+64]} at pair index j, so recurrent
// lane l loads its two gate columns {l, l+64} with one global_load_dwordx2.
__global__ __launch_bounds__(128) void embw_kernel(
    const float* __restrict__ emb, const float* __restrict__ W1,
    const float* __restrict__ b1, float* __restrict__ embW)
{
    const int v = blockIdx.x, c = threadIdx.x;
    __shared__ float e[32];
    if (c < 32) e[c] = emb[v * 32 + c];
    __syncthreads();
    float acc = b1[c];
#pragma unroll
    for (int d = 0; d < 32; ++d) acc = fmaf(e[d], W1[d * 128 + c], acc);
    embW[v * 128 + ((c & 63) << 1) + (c >> 6)] = acc;
}

// ---------------- pass 2: recurrent kernel ----------------
// One wave = one batch element. Lane l owns gate columns ca=l (i|f), cb=l+64
// (g|o). Input part gathered from embW (f32). h@U1 and h@W2 both via
// v_dot2_f32_f16 consuming the SAME 16 readlane'd h-pair SGPRs; layer 2 runs
// one step behind so its chain overlaps the U-matvec (ILP, off critical path).
// Zero DS cross-lane ops: DPP for lane^1, permlane32_swap for half exchange.
template<int MODE>
__global__ __launch_bounds__(256) void lstm_kernel(
    const int* __restrict__ x, const float* __restrict__ embW,
    const float* __restrict__ emb, const float* __restrict__ W1,
    const float* __restrict__ b1, const float* __restrict__ U1,
    const float* __restrict__ W2, const float* __restrict__ U2,
    const float* __restrict__ b2, float* __restrict__ out, int T)
{
    const int lane = threadIdx.x & 63;
    const int wave = threadIdx.x >> 6;
    const int b    = blockIdx.x * 4 + wave;
    const bool low = lane < 32;
    const int ca = lane, cb = lane + 64;

    // U1 columns as packed-f16 k-pairs: 32 VGPRs
    h2v upa[16], upb[16];
#pragma unroll
    for (int m = 0; m < 16; ++m) {
        h2v ta, tb;
        ta[0] = (__fp16)U1[(2 * m) * 128 + ca];
        ta[1] = (__fp16)U1[(2 * m + 1) * 128 + ca];
        tb[0] = (__fp16)U1[(2 * m) * 128 + cb];
        tb[1] = (__fp16)U1[(2 * m + 1) * 128 + cb];
        upa[m] = ta; upb[m] = tb;
    }

    h2v wpa[16], wpb[16];            // MODE1 only (DCE'd in MODE0)
    float ba = 0.f, bb = 0.f;
    if constexpr (MODE == 1) {
#pragma unroll
        for (int m = 0; m < 16; ++m) {
            h2v ta, tb;
            ta[0] = (__fp16)W1[(2 * m) * 128 + ca];
            ta[1] = (__fp16)W1[(2 * m + 1) * 128 + ca];
            tb[0] = (__fp16)W1[(2 * m) * 128 + cb];
            tb[1] = (__fp16)W1[(2 * m + 1) * 128 + cb];
            wpa[m] = ta; wpb[m] = tb;
        }
        ba = b1[ca]; bb = b1[cb];
    }

    // layer 2 (H=1): 16-lane group gsel = lane>>4 redundantly computes gate
    // gsel's full 32-dot from the shared h-pair SGPRs. Gate order i,f,g,o.
    const int gsel = lane >> 4;
    h2v w2p[16];
#pragma unroll
    for (int m = 0; m < 16; ++m) {
        h2v tw;
        tw[0] = (__fp16)W2[(2 * m) * 4 + gsel];
        tw[1] = (__fp16)W2[(2 * m + 1) * 4 + gsel];
        w2p[m] = tw;
    }
    const float u2s = U2[gsel];
    const float b2s = b2[gsel];

    const int* xrow = x + b * T;

    float h = 0.f, c = 0.f, h2 = 0.f, c2 = 0.f;
    int hp[16];   // readlane'd h-pair broadcasts (SGPRs), shared by U1 & W2 dots

#define LAYER2_UPDATE()                                                        \
    do {                                                                       \
        float p0 = 0.f, p1 = 0.f;                                              \
        _Pragma("unroll")                                                      \
        for (int m = 0; m < 16; m += 2) {                                      \
            p0 = fdot2(__builtin_bit_cast(h2v, hp[m]),     w2p[m],     p0);    \
            p1 = fdot2(__builtin_bit_cast(h2v, hp[m + 1]), w2p[m + 1], p1);    \
        }                                                                      \
        float s2 = sigmoid_f((p0 + p1) + fmaf(u2s, h2, b2s));                  \
        float i2 = rlf(s2, 0),  f2 = rlf(s2, 16);                              \
        float g2 = rlf(s2, 32), o2 = rlf(s2, 48);                              \
        c2 = fmaf(f2, c2, i2 * g2);                                            \
        h2 = o2 * sigmoid_f(c2);                                               \
    } while (0)

    int idxA = __builtin_amdgcn_readfirstlane(xrow[0]);
    int idxB = __builtin_amdgcn_readfirstlane(xrow[1]);

    v2f zc;           // {z[ca], z[cb]} input part for current t (MODE0)
    float ec[32];     // e row for current t (MODE1)
    if constexpr (MODE == 0) {
        zc = reinterpret_cast<const v2f*>(embW)[idxA * 64 + lane];
    } else {
#pragma unroll
        for (int d = 0; d < 32; ++d) ec[d] = emb[idxA * 32 + d];
    }

#pragma unroll 2
    for (int t = 0; t < T; ++t) {
        // ---- prefetch input contribution for t+1 ----
        v2f zn;
        float en[32];
        if constexpr (MODE == 0) {
            zn = reinterpret_cast<const v2f*>(embW)[idxB * 64 + lane];
        } else {
#pragma unroll
            for (int d = 0; d < 32; ++d) en[d] = emb[idxB * 32 + d];
        }
        idxB = __builtin_amdgcn_readfirstlane(xrow[(t + 2 < T) ? (t + 2) : (T - 1)]);

        // ---- pack h_{t-1} pairs and broadcast to SGPRs (shared by both dots) ----
        float hx = dpp_swap1(h);
        int hpi = __builtin_bit_cast(int, __builtin_amdgcn_cvt_pkrtz(h, hx));
#pragma unroll
        for (int m = 0; m < 16; ++m) hp[m] = rl_i(hpi, 2 * m);

        // ---- z = z_input + h_{t-1} @ U1 (4 independent dot2 chains) ----
        float za0, zb0;
        if constexpr (MODE == 0) {
            za0 = zc.x; zb0 = zc.y;
        } else {
            za0 = ba; zb0 = bb;
#pragma unroll
            for (int m = 0; m < 16; ++m) {
                h2v ep = __builtin_amdgcn_cvt_pkrtz(ec[2 * m], ec[2 * m + 1]);
                za0 = fdot2(ep, wpa[m], za0);
                zb0 = fdot2(ep, wpb[m], zb0);
            }
        }
        float za1 = 0.f, zb1 = 0.f;
#pragma unroll
        for (int m = 0; m < 16; m += 2) {
            h2v h0 = __builtin_bit_cast(h2v, hp[m]);
            h2v h1 = __builtin_bit_cast(h2v, hp[m + 1]);
            za0 = fdot2(h0, upa[m],     za0);
            zb0 = fdot2(h0, upb[m],     zb0);
            za1 = fdot2(h1, upa[m + 1], za1);
            zb1 = fdot2(h1, upb[m + 1], zb1);
        }
        const float za = za0 + za1;   // z_i (low) | z_f (high)
        const float zb = zb0 + zb1;   // z_g (low) | z_o (high)

        // ---- layer 2 step t-1 (parallel ILP chain, uses same hp) ----
        if (t) LAYER2_UPDATE();

        // ---- layer-1 gates ----
        float sa = sigmoid_f(za);                 // sig(i) | sig(f)
        float xb_ = low ? 2.0f * zb : zb;
        float u  = sigmoid_f(xb_);
        float rb = low ? 2.0f * u - 1.0f : u;     // tanh(g) | sig(o)

        float iv, fv, gv, ov;
        bcast_halves(sa, low, iv, fv);            // i, f broadcast to all lanes
        bcast_halves(rb, low, gv, ov);            // g, o broadcast to all lanes

        c = fmaf(fv, c, iv * gv);
        float tc = 2.0f * sigmoid_f(2.0f * c) - 1.0f;   // tanh(c)
        h = ov * tc;                               // h[l] = h[l&31]

        // rotate input buffers
        if constexpr (MODE == 0) {
            zc = zn;
        } else {
#pragma unroll
            for (int d = 0; d < 32; ++d) ec[d] = en[d];
        }
    }

    // ---- epilogue: layer 2 for final step T-1 ----
    {
        float hx = dpp_swap1(h);
        int hpi = __builtin_bit_cast(int, __builtin_amdgcn_cvt_pkrtz(h, hx));
#pragma unroll
        for (int m = 0; m < 16; ++m) hp[m] = rl_i(hpi, 2 * m);
        LAYER2_UPDATE();
    }

    if (lane == 0) out[b] = h2;
#undef LAYER2_UPDATE
}

extern "C" void kernel_launch(void* const* d_in, const int* in_sizes, int n_in,
                              void* d_out, int out_size, void* d_ws, size_t ws_size,
                              hipStream_t stream) {
    const int*   x   = (const int*)d_in[0];
    const float* emb = (const float*)d_in[1];
    const float* W1  = (const float*)d_in[2];
    const float* U1  = (const float*)d_in[3];
    const float* b1  = (const float*)d_in[4];
    const float* W2  = (const float*)d_in[5];
    const float* U2  = (const float*)d_in[6];
    const float* b2  = (const float*)d_in[7];
    float* out = (float*)d_out;

    const int V = in_sizes[1] / 32;       // vocab (30000)
    const int T = 200;
    const int B = in_sizes[0] / T;        // 4096
    const int blocks = B / 4;

    const size_t need = (size_t)V * 128 * sizeof(float);   // 15.36 MB
    if (ws_size >= need) {
        float* embW = (float*)d_ws;
        embw_kernel<<<V, 128, 0, stream>>>(emb, W1, b1, embW);
        lstm_kernel<0><<<blocks, 256, 0, stream>>>(x, embW, emb, W1, b1, U1,
                                                   W2, U2, b2, out, T);
    } else {
        lstm_kernel<1><<<blocks, 256, 0, stream>>>(x, nullptr, emb, W1, b1, U1,
                                                   W2, U2, b2, out, T);
    }
}